// Round 16
// baseline (225.728 us; speedup 1.0000x reference)
//
#include <hip/hip_runtime.h>
#include <math.h>

#define HD    128
#define NQH   32
#define NKVH  8
#define GQA   4
#define PBLK  16      // paged cache block size
#define MAXNB 512     // max block-table entries cached in LDS
#define BATCH 8       // tokens per inner iteration per half-wave

#define L2_10000 13.287712379549449f   // log2(10000)

typedef float f4 __attribute__((ext_vector_type(4)));
typedef float f2 __attribute__((ext_vector_type(2)));

__device__ __forceinline__ f4 ldnt4(const float* p) {
    return __builtin_nontemporal_load((const f4*)p);
}
__device__ __forceinline__ f2 ldnt2(const float* p) {
    return __builtin_nontemporal_load((const f2*)p);
}

// R15 champion (101.5us e2e) with BATCH 4->8: 24 VMEM in flight per wave,
// halves the number of serialization points where the next batch's loads
// wait on this batch's softmax tail. 512MB stream, ~84% of the 6.3TB/s
// copy ceiling already; floor ~86us e2e.
__global__ __launch_bounds__(1024) void paged_attn_kernel(
    const float* __restrict__ q,
    const float* __restrict__ kcur,
    const float* __restrict__ vcur,
    const float* __restrict__ kc,
    const float* __restrict__ vc,
    const int* __restrict__ bt,
    float* __restrict__ out,
    int T, int nb)
{
    const int b   = blockIdx.x >> 3;
    const int h   = blockIdx.x & 7;
    const int tid = threadIdx.x;
    const int hw  = tid >> 5;        // half-wave id 0..31
    const int il  = tid & 31;        // lane within half-wave
    const int d0v = il << 2;         // V/output dims [d0v, d0v+4)
    const int dk  = il << 1;         // K dims: {dk,dk+1} and {64+dk, 64+dk+1}

    // cache block table row in LDS
    __shared__ int sbt[MAXNB];
    const int* btrow = bt + (size_t)b * nb;
    if (nb <= MAXNB) {
        for (int i = tid; i < nb; i += 1024) sbt[i] = btrow[i];
        __syncthreads();
        btrow = sbt;
    }

    // this lane's two rope frequencies
    const float invf0 = exp2f(-(float)(dk)     * (L2_10000 / 64.0f));
    const float invf1 = exp2f(-(float)(dk + 1) * (L2_10000 / 64.0f));
    const float scale = 0.08838834764831845f;  // 128^-0.5

    // --- rope current q (4 GQA heads) at position T, scale folded in ---
    f4 qr[4];
    {
        float cT0, sT0, cT1, sT1;
        sincosf((float)T * invf0, &sT0, &cT0);
        sincosf((float)T * invf1, &sT1, &cT1);
        const float* qb = q + ((size_t)b * NQH + h * GQA) * HD;
#pragma unroll
        for (int g = 0; g < 4; ++g) {
            f2 xlo = *(const f2*)(qb + (size_t)g * HD + dk);
            f2 xhi = *(const f2*)(qb + (size_t)g * HD + 64 + dk);
            qr[g].x = (xlo.x * cT0 - xhi.x * sT0) * scale;
            qr[g].y = (xlo.y * cT1 - xhi.y * sT1) * scale;
            qr[g].z = (xhi.x * cT0 + xlo.x * sT0) * scale;
            qr[g].w = (xhi.y * cT1 + xlo.y * sT1) * scale;
        }
    }

    // --- rope phase recurrence: state at token hw; rotor advances 32 ---
    float c0, s0c, c1, s1c, C0, S0, C1, S1;
    sincosf((float)hw * invf0, &s0c, &c0);
    sincosf((float)hw * invf1, &s1c, &c1);
    sincosf(32.0f * invf0, &S0, &C0);
    sincosf(32.0f * invf1, &S1, &C1);

    float m[4] = {-INFINITY, -INFINITY, -INFINITY, -INFINITY};
    float l[4] = {0.f, 0.f, 0.f, 0.f};
    f4 o[4] = {};

    const float* kcurp = kcur + ((size_t)b * NKVH + h) * HD;
    const float* vcurp = vcur + ((size_t)b * NKVH + h) * HD;

    // --- main loop: half-wave takes BATCH tokens per iteration: t0+32j ---
    for (int t0 = hw; t0 <= T; t0 += 32 * BATCH) {
        f2 klo[BATCH], khi[BATCH];
        f4 vv[BATCH];
        // issue all loads back-to-back (3*BATCH VMEM in flight), nontemporal
#pragma unroll
        for (int j = 0; j < BATCH; ++j) {
            int tj = t0 + 32 * j;
            int tc = (tj <= T) ? tj : hw;         // clamped: always in-bounds
            const float *kb, *vb;
            if (tc == T) { kb = kcurp; vb = vcurp; }
            else {
                int blk = btrow[tc >> 4];
                size_t off = (((size_t)blk * PBLK + (tc & (PBLK - 1))) * NKVH + h) * HD;
                kb = kc + off; vb = vc + off;
            }
            klo[j] = ldnt2(kb + dk);
            khi[j] = ldnt2(kb + 64 + dk);
            vv[j]  = ldnt4(vb + d0v);
        }

        // rope + dot partials for all BATCH tokens
        float v[BATCH][4];
#pragma unroll
        for (int j = 0; j < BATCH; ++j) {
            f4 kr;
            kr.x = klo[j].x * c0 - khi[j].x * s0c;
            kr.y = klo[j].y * c1 - khi[j].y * s1c;
            kr.z = khi[j].x * c0 + klo[j].x * s0c;
            kr.w = khi[j].y * c1 + klo[j].y * s1c;
            {   // advance phase by 32 positions (complex multiply)
                float nc0 = c0 * C0 - s0c * S0, ns0 = s0c * C0 + c0 * S0;
                float nc1 = c1 * C1 - s1c * S1, ns1 = s1c * C1 + c1 * S1;
                c0 = nc0; s0c = ns0; c1 = nc1; s1c = ns1;
            }
#pragma unroll
            for (int g = 0; g < 4; ++g)
                v[j][g] = qr[g].x * kr.x + qr[g].y * kr.y
                        + qr[g].z * kr.z + qr[g].w * kr.w;
        }

        // butterfly reduce: BATCH*4 independent shuffles per stage, 5 stages
#pragma unroll
        for (int msk = 16; msk >= 1; msk >>= 1) {
#pragma unroll
            for (int j = 0; j < BATCH; ++j) {
#pragma unroll
                for (int g = 0; g < 4; ++g)
                    v[j][g] += __shfl_xor(v[j][g], msk);
            }
        }

        // online softmax updates
#pragma unroll
        for (int j = 0; j < BATCH; ++j) {
            bool valid = (t0 + 32 * j <= T);
#pragma unroll
            for (int g = 0; g < 4; ++g) {
                float sc = valid ? v[j][g] : -INFINITY;
                if (sc > m[g]) {                 // lazy rescale: rare
                    float corr = __expf(m[g] - sc);
                    l[g] *= corr;
                    o[g] *= corr;
                    m[g] = sc;
                }
                float p = __expf(sc - m[g]);     // exp(-inf)=0 for invalid
                l[g] += p;
                o[g] += p * vv[j];
            }
        }
    }

    // --- combine the two half-waves of each wave ---
#pragma unroll
    for (int g = 0; g < 4; ++g) {
        float mo = __shfl_xor(m[g], 32);
        float M  = fmaxf(m[g], mo);
        float w  = (m[g] > -INFINITY) ? __expf(m[g] - M) : 0.f;
        float lw = l[g] * w;
        float Lc = lw + __shfl_xor(lw, 32);
        f4 ow = o[g] * w;
        f4 Oc;
        Oc.x = ow.x + __shfl_xor(ow.x, 32);
        Oc.y = ow.y + __shfl_xor(ow.y, 32);
        Oc.z = ow.z + __shfl_xor(ow.z, 32);
        Oc.w = ow.w + __shfl_xor(ow.w, 32);
        m[g] = M; l[g] = Lc; o[g] = Oc;
    }

    // --- cross-wave flash combine via LDS ---
    __shared__ float lm[16][4];
    __shared__ float ll[16][4];
    __shared__ float lodata[16][4][HD];
    const int w = tid >> 6;
    if ((tid & 32) == 0) {
        if (il == 0) {
#pragma unroll
            for (int g = 0; g < 4; ++g) { lm[w][g] = m[g]; ll[w][g] = l[g]; }
        }
#pragma unroll
        for (int g = 0; g < 4; ++g)
            *(f4*)(&lodata[w][g][d0v]) = o[g];
    }
    __syncthreads();

    if (tid < 512) {
        int g = tid >> 7;
        int d = tid & 127;
        float M = -INFINITY;
#pragma unroll
        for (int i = 0; i < 16; ++i) M = fmaxf(M, lm[i][g]);
        float L = 0.f, O = 0.f;
#pragma unroll
        for (int i = 0; i < 16; ++i) {
            float wgt = __expf(lm[i][g] - M);
            L += wgt * ll[i][g];
            O += wgt * lodata[i][g][d];
        }
        out[(size_t)b * (NQH * HD) + (size_t)(h * GQA + g) * HD + d] = O / L;
    }
}

extern "C" void kernel_launch(void* const* d_in, const int* in_sizes, int n_in,
                              void* d_out, int out_size, void* d_ws, size_t ws_size,
                              hipStream_t stream) {
    const float* q  = (const float*)d_in[0];
    const float* k  = (const float*)d_in[1];
    const float* v  = (const float*)d_in[2];
    const float* kc = (const float*)d_in[3];
    const float* vc = (const float*)d_in[4];
    const int*   bt = (const int*)d_in[5];
    int B  = in_sizes[0] / (NQH * HD);
    int nb = in_sizes[5] / B;
    int T  = nb * PBLK;

    float* out = (float*)d_out;
    paged_attn_kernel<<<B * NKVH, 1024, 0, stream>>>(q, k, v, kc, vc, bt, out, T, nb);
}

// Round 17
// 101.481 us; speedup vs baseline: 2.2243x; 2.2243x over previous
//
#include <hip/hip_runtime.h>
#include <math.h>

#define HD    128
#define NQH   32
#define NKVH  8
#define GQA   4
#define PBLK  16      // paged cache block size
#define MAXNB 512     // max block-table entries cached in LDS
#define BATCH 4       // tokens per inner iteration per half-wave

#define L2_10000 13.287712379549449f   // log2(10000)

typedef float f4 __attribute__((ext_vector_type(4)));
typedef float f2 __attribute__((ext_vector_type(2)));

__device__ __forceinline__ f4 ldnt4(const float* p) {
    return __builtin_nontemporal_load((const f4*)p);
}
__device__ __forceinline__ f2 ldnt2(const float* p) {
    return __builtin_nontemporal_load((const f2*)p);
}

// R15 champion (101.5us e2e), reverted verbatim after BATCH=8 spilled
// (r16: VGPR capped at 64 -> 285MB scratch writes, 225us). BATCH=4 keeps
// the 12-load in-flight window inside the 64-VGPR allocation. 512MB KV
// stream at ~5.3TB/s effective = ~85% of the 6.3TB/s copy ceiling.
__global__ __launch_bounds__(1024) void paged_attn_kernel(
    const float* __restrict__ q,
    const float* __restrict__ kcur,
    const float* __restrict__ vcur,
    const float* __restrict__ kc,
    const float* __restrict__ vc,
    const int* __restrict__ bt,
    float* __restrict__ out,
    int T, int nb)
{
    const int b   = blockIdx.x >> 3;
    const int h   = blockIdx.x & 7;
    const int tid = threadIdx.x;
    const int hw  = tid >> 5;        // half-wave id 0..31
    const int il  = tid & 31;        // lane within half-wave
    const int d0v = il << 2;         // V/output dims [d0v, d0v+4)
    const int dk  = il << 1;         // K dims: {dk,dk+1} and {64+dk, 64+dk+1}

    // cache block table row in LDS
    __shared__ int sbt[MAXNB];
    const int* btrow = bt + (size_t)b * nb;
    if (nb <= MAXNB) {
        for (int i = tid; i < nb; i += 1024) sbt[i] = btrow[i];
        __syncthreads();
        btrow = sbt;
    }

    // this lane's two rope frequencies
    const float invf0 = exp2f(-(float)(dk)     * (L2_10000 / 64.0f));
    const float invf1 = exp2f(-(float)(dk + 1) * (L2_10000 / 64.0f));
    const float scale = 0.08838834764831845f;  // 128^-0.5

    // --- rope current q (4 GQA heads) at position T, scale folded in ---
    f4 qr[4];
    {
        float cT0, sT0, cT1, sT1;
        sincosf((float)T * invf0, &sT0, &cT0);
        sincosf((float)T * invf1, &sT1, &cT1);
        const float* qb = q + ((size_t)b * NQH + h * GQA) * HD;
#pragma unroll
        for (int g = 0; g < 4; ++g) {
            f2 xlo = *(const f2*)(qb + (size_t)g * HD + dk);
            f2 xhi = *(const f2*)(qb + (size_t)g * HD + 64 + dk);
            qr[g].x = (xlo.x * cT0 - xhi.x * sT0) * scale;
            qr[g].y = (xlo.y * cT1 - xhi.y * sT1) * scale;
            qr[g].z = (xhi.x * cT0 + xlo.x * sT0) * scale;
            qr[g].w = (xhi.y * cT1 + xlo.y * sT1) * scale;
        }
    }

    // --- rope phase recurrence: state at token hw; rotor advances 32 ---
    float c0, s0c, c1, s1c, C0, S0, C1, S1;
    sincosf((float)hw * invf0, &s0c, &c0);
    sincosf((float)hw * invf1, &s1c, &c1);
    sincosf(32.0f * invf0, &S0, &C0);
    sincosf(32.0f * invf1, &S1, &C1);

    float m[4] = {-INFINITY, -INFINITY, -INFINITY, -INFINITY};
    float l[4] = {0.f, 0.f, 0.f, 0.f};
    f4 o[4] = {};

    const float* kcurp = kcur + ((size_t)b * NKVH + h) * HD;
    const float* vcurp = vcur + ((size_t)b * NKVH + h) * HD;

    // --- main loop: half-wave takes BATCH tokens per iteration: t0+32j ---
    for (int t0 = hw; t0 <= T; t0 += 32 * BATCH) {
        f2 klo[BATCH], khi[BATCH];
        f4 vv[BATCH];
        bool valid[BATCH];
        // issue all loads back-to-back (12 VMEM in flight), nontemporal
#pragma unroll
        for (int j = 0; j < BATCH; ++j) {
            int tj = t0 + 32 * j;
            valid[j] = (tj <= T);
            int tc = valid[j] ? tj : hw;          // clamped: always in-bounds
            const float *kb, *vb;
            if (tc == T) { kb = kcurp; vb = vcurp; }
            else {
                int blk = btrow[tc >> 4];
                size_t off = (((size_t)blk * PBLK + (tc & (PBLK - 1))) * NKVH + h) * HD;
                kb = kc + off; vb = vc + off;
            }
            klo[j] = ldnt2(kb + dk);
            khi[j] = ldnt2(kb + 64 + dk);
            vv[j]  = ldnt4(vb + d0v);
        }

        // rope + dot partials for all BATCH tokens
        float v[BATCH][4];
#pragma unroll
        for (int j = 0; j < BATCH; ++j) {
            f4 kr;
            kr.x = klo[j].x * c0 - khi[j].x * s0c;
            kr.y = klo[j].y * c1 - khi[j].y * s1c;
            kr.z = khi[j].x * c0 + klo[j].x * s0c;
            kr.w = khi[j].y * c1 + klo[j].y * s1c;
            {   // advance phase by 32 positions (complex multiply)
                float nc0 = c0 * C0 - s0c * S0, ns0 = s0c * C0 + c0 * S0;
                float nc1 = c1 * C1 - s1c * S1, ns1 = s1c * C1 + c1 * S1;
                c0 = nc0; s0c = ns0; c1 = nc1; s1c = ns1;
            }
#pragma unroll
            for (int g = 0; g < 4; ++g)
                v[j][g] = qr[g].x * kr.x + qr[g].y * kr.y
                        + qr[g].z * kr.z + qr[g].w * kr.w;
        }

        // butterfly reduce: 16 independent shuffles per stage, 5 stages
#pragma unroll
        for (int msk = 16; msk >= 1; msk >>= 1) {
#pragma unroll
            for (int j = 0; j < BATCH; ++j) {
#pragma unroll
                for (int g = 0; g < 4; ++g)
                    v[j][g] += __shfl_xor(v[j][g], msk);
            }
        }

        // online softmax updates
#pragma unroll
        for (int j = 0; j < BATCH; ++j) {
#pragma unroll
            for (int g = 0; g < 4; ++g) {
                float sc = valid[j] ? v[j][g] : -INFINITY;
                if (sc > m[g]) {                 // lazy rescale: rare
                    float corr = __expf(m[g] - sc);
                    l[g] *= corr;
                    o[g] *= corr;
                    m[g] = sc;
                }
                float p = __expf(sc - m[g]);     // exp(-inf)=0 for invalid
                l[g] += p;
                o[g] += p * vv[j];
            }
        }
    }

    // --- combine the two half-waves of each wave ---
#pragma unroll
    for (int g = 0; g < 4; ++g) {
        float mo = __shfl_xor(m[g], 32);
        float M  = fmaxf(m[g], mo);
        float w  = (m[g] > -INFINITY) ? __expf(m[g] - M) : 0.f;
        float lw = l[g] * w;
        float Lc = lw + __shfl_xor(lw, 32);
        f4 ow = o[g] * w;
        f4 Oc;
        Oc.x = ow.x + __shfl_xor(ow.x, 32);
        Oc.y = ow.y + __shfl_xor(ow.y, 32);
        Oc.z = ow.z + __shfl_xor(ow.z, 32);
        Oc.w = ow.w + __shfl_xor(ow.w, 32);
        m[g] = M; l[g] = Lc; o[g] = Oc;
    }

    // --- cross-wave flash combine via LDS ---
    __shared__ float lm[16][4];
    __shared__ float ll[16][4];
    __shared__ float lodata[16][4][HD];
    const int w = tid >> 6;
    if ((tid & 32) == 0) {
        if (il == 0) {
#pragma unroll
            for (int g = 0; g < 4; ++g) { lm[w][g] = m[g]; ll[w][g] = l[g]; }
        }
#pragma unroll
        for (int g = 0; g < 4; ++g)
            *(f4*)(&lodata[w][g][d0v]) = o[g];
    }
    __syncthreads();

    if (tid < 512) {
        int g = tid >> 7;
        int d = tid & 127;
        float M = -INFINITY;
#pragma unroll
        for (int i = 0; i < 16; ++i) M = fmaxf(M, lm[i][g]);
        float L = 0.f, O = 0.f;
#pragma unroll
        for (int i = 0; i < 16; ++i) {
            float wgt = __expf(lm[i][g] - M);
            L += wgt * ll[i][g];
            O += wgt * lodata[i][g][d];
        }
        out[(size_t)b * (NQH * HD) + (size_t)(h * GQA + g) * HD + d] = O / L;
    }
}

extern "C" void kernel_launch(void* const* d_in, const int* in_sizes, int n_in,
                              void* d_out, int out_size, void* d_ws, size_t ws_size,
                              hipStream_t stream) {
    const float* q  = (const float*)d_in[0];
    const float* k  = (const float*)d_in[1];
    const float* v  = (const float*)d_in[2];
    const float* kc = (const float*)d_in[3];
    const float* vc = (const float*)d_in[4];
    const int*   bt = (const int*)d_in[5];
    int B  = in_sizes[0] / (NQH * HD);
    int nb = in_sizes[5] / B;
    int T  = nb * PBLK;

    float* out = (float*)d_out;
    paged_attn_kernel<<<B * NKVH, 1024, 0, stream>>>(q, k, v, kc, vc, bt, out, T, nb);
}